// Round 1
// baseline (93.400 us; speedup 1.0000x reference)
//
#include <hip/hip_runtime.h>
#include <math.h>

#define BLOCK 256
#define LBv 1e-20f
#define UBv 1e20f

// Raw HW transcendentals: v_log_f32 / v_exp_f32 (~1 ulp).
// Edge semantics used deliberately: log2(0) = -inf, exp2(-inf) = 0 (c1>0).
#if __has_builtin(__builtin_amdgcn_logf) && __has_builtin(__builtin_amdgcn_exp2f)
__device__ __forceinline__ float fast_log2(float x) { return __builtin_amdgcn_logf(x); }
__device__ __forceinline__ float fast_exp2(float x) { return __builtin_amdgcn_exp2f(x); }
#else
__device__ __forceinline__ float fast_log2(float x) { return log2f(x); }
__device__ __forceinline__ float fast_exp2(float x) { return exp2f(x); }
#endif

__global__ __launch_bounds__(BLOCK, 4) void mcnet_sreg(
    const float* __restrict__ verts,   // (NT, V, 3) f32
    const float* __restrict__ smooth,  // (NT,)      f32
    const float* __restrict__ dirs,    // (D, 3)     f32
    float* __restrict__ out,           // f32, chunks concatenated flat
    int NT, int V, int D, int SPLIT,
    size_t offDH, size_t offMV, size_t offDIR, size_t offLV, size_t offZ)
{
    __shared__ float red[12];          // 4 waves x 3 partials

    const int tid  = threadIdx.x;
    const int lane = tid & 63;
    const int wid  = tid >> 6;
    const int tile = blockIdx.x / SPLIT;
    const int s    = blockIdx.x % SPLIT;

    const float* vp0 = verts + (size_t)tile * V * 3;

    // ---- mean: per-thread partial -> wave shfl_xor reduce -> 1 barrier ----
    float sx = 0.f, sy = 0.f, sz = 0.f;
    for (int v = tid; v < V; v += BLOCK) {
        sx += vp0[3 * v + 0]; sy += vp0[3 * v + 1]; sz += vp0[3 * v + 2];
    }
    #pragma unroll
    for (int off = 32; off > 0; off >>= 1) {
        sx += __shfl_xor(sx, off);
        sy += __shfl_xor(sy, off);
        sz += __shfl_xor(sz, off);
    }
    if (lane == 0) { red[wid * 3 + 0] = sx; red[wid * 3 + 1] = sy; red[wid * 3 + 2] = sz; }
    __syncthreads();
    const float inv = 1.0f / (float)V;
    const float mx = (red[0] + red[3] + red[6] + red[9])  * inv;
    const float my = (red[1] + red[4] + red[7] + red[10]) * inv;
    const float mz = (red[2] + red[5] + red[8] + red[11]) * inv;

    // ---- small outputs ----
    if (s == 0) {
        for (int v = tid; v < V; v += BLOCK) {
            size_t o = offLV + ((size_t)tile * V + v) * 3;
            out[o + 0] = vp0[3 * v + 0] - mx;
            out[o + 1] = vp0[3 * v + 1] - my;
            out[o + 2] = vp0[3 * v + 2] - mz;
        }
        if (tid == 0) {
            size_t mo = offMV + (size_t)tile * 3;
            out[mo + 0] = mx;
            out[mo + 1] = my;
            out[mo + 2] = mz;
        }
    }
    if (blockIdx.x == 0) {
        for (int i = tid; i < D * 3; i += BLOCK)
            out[offDIR + i] = dirs[i];
        if (tid < 2) out[offZ + tid] = 0.f;
    }

    // ---- one direction per thread ----
    const int d0 = s * BLOCK + tid;
    // wave-uniform exit for fully-dead waves (keeps control flow uniform so
    // the vertex loads scalarize to s_load; the one partial wave clamps d and
    // predicates its stores).
    if (__builtin_amdgcn_readfirstlane(d0) >= D) return;
    const bool active = (d0 < D);
    const int  d      = active ? d0 : (D - 1);

    const float dx = dirs[d * 3 + 0];
    const float dy = dirs[d * 3 + 1];
    const float dz = dirs[d * 3 + 2];
    const float pv = smooth[tile];
    const float c1 = pv - 1.f;
    const float Sthresh = (float)V * 1e-10f;

    // z = v.d - m.d : wave-uniform vertex reads (s_load), unnormalized sums,
    // mean-correct in the epilogue: sum w*lv = (sum w*v) - m*(sum w)
    const float nmd = -(mx * dx + my * dy + mz * dz);

    float S = 0.f, Wx = 0.f, Wy = 0.f, Wz = 0.f, Ws = 0.f;

#define PROC1(vx, vy, vz) do {                                     \
        float z  = fmaf((vx), dx, fmaf((vy), dy, fmaf((vz), dz, nmd))); \
        float zc = fmaxf(z, 0.f);                                  \
        float l  = fast_log2(zc);          /* -inf at 0 */         \
        float w  = fast_exp2(c1 * l);      /* z^(p-1), 0 at z<=0 */\
        S  = fmaf(w, zc, S);                                       \
        Wx = fmaf(w, (vx), Wx);                                    \
        Wy = fmaf(w, (vy), Wy);                                    \
        Wz = fmaf(w, (vz), Wz);                                    \
        Ws += w;                                                   \
    } while (0)

#define PROC4(q0, q1, q2) do {                                     \
        PROC1(q0.x, q0.y, q0.z); PROC1(q0.w, q1.x, q1.y);          \
        PROC1(q1.z, q1.w, q2.x); PROC1(q2.y, q2.z, q2.w);          \
    } while (0)

    if ((V & 7) == 0) {
        // software-pipelined: prefetch next half-stage (3x float4 = 4 verts)
        // while computing the current one; one half-stage of compute (~112 cy)
        // always covers the load latency.
        const float4* vp4 = (const float4*)vp0;   // V*3/4 float4s, 16B-aligned
        const int NS = V >> 3;                     // 8 verts / iteration
        float4 a0 = vp4[0], a1 = vp4[1], a2 = vp4[2];
        float4 b0 = vp4[3], b1 = vp4[4], b2 = vp4[5];
        for (int st = 0; st < NS - 1; ++st) {
            const float4* nxt = vp4 + st * 6 + 6;
            float4 t0 = a0, t1 = a1, t2 = a2;
            a0 = nxt[0]; a1 = nxt[1]; a2 = nxt[2];
            PROC4(t0, t1, t2);
            t0 = b0; t1 = b1; t2 = b2;
            b0 = nxt[3]; b1 = nxt[4]; b2 = nxt[5];
            PROC4(t0, t1, t2);
        }
        PROC4(a0, a1, a2);
        PROC4(b0, b1, b2);
    } else {
        #pragma unroll 8
        for (int v = 0; v < V; ++v)
            PROC1(vp0[3 * v + 0], vp0[3 * v + 1], vp0[3 * v + 2]);
    }

    if (!active) return;

    size_t po  = ((size_t)tile * D + d) * 3;
    size_t dho = offDH + ((size_t)tile * D + d) * 4;

    if (S >= Sthresh) {
        // S >= V*1e-10 => zmax^p >= 1e-10: no k-rescale, exponents bounded,
        // LB floors negligible, UB clip unreachable.
        float h = fminf(fmaxf(fast_exp2(fast_log2(S) * (1.f / pv)), LBv), UBv);
        float scale = fast_exp2(-c1 * fast_log2(h));   // h^-(p-1)
        float ax = fmaf(-mx, Ws, Wx);                  // sum w*lv
        float ay = fmaf(-my, Ws, Wy);
        float az = fmaf(-mz, Ws, Wz);
        out[po + 0] = fmaf(ax, scale, mx);
        out[po + 1] = fmaf(ay, scale, my);
        out[po + 2] = fmaf(az, scale, mz);
        out[dho + 0] = dx;
        out[dho + 1] = dy;
        out[dho + 2] = dz;
        out[dho + 3] = h;                               // k == 1
    } else {
        // ---- literal reference semantics (cold; never taken for bench data) ----
        float zmax = 0.f;
        for (int v = 0; v < V; ++v) {
            float z = fmaf(vp0[3 * v] - mx, dx,
                      fmaf(vp0[3 * v + 1] - my, dy, (vp0[3 * v + 2] - mz) * dz));
            zmax = fmaxf(zmax, z);
        }
        float zm_log   = (zmax > 0.f) ? log10f(zmax) : -INFINITY;
        float exponent = zm_log * pv;
        float lk = (exponent < -20.f) ? (-20.f - exponent) / pv : 0.f;
        float kk = powf(10.f, fminf(fmaxf(ceilf(lk), 0.f), UBv));

        float sum = 0.f;
        for (int v = 0; v < V; ++v) {
            float z = fmaf(vp0[3 * v] - mx, dx,
                      fmaf(vp0[3 * v + 1] - my, dy, (vp0[3 * v + 2] - mz) * dz));
            float zms = fmaxf(z, 0.f) * kk;
            float w   = (zms > 0.f) ? fminf(fmaxf(powf(zms, pv), LBv), UBv) : 0.f;
            sum += w;
        }
        float h = fminf(fmaxf(powf(sum, 1.f / pv), LBv), UBv);

        float bx = 0.f, by = 0.f, bz = 0.f;
        for (int v = 0; v < V; ++v) {
            float lx = vp0[3 * v] - mx, ly = vp0[3 * v + 1] - my, lz = vp0[3 * v + 2] - mz;
            float z     = fmaf(lx, dx, fmaf(ly, dy, lz * dz));
            float zms   = fmaxf(z, 0.f) * kk;
            float ratio = zms / h;
            float w = (ratio > 0.f) ? fminf(fmaxf(powf(ratio, c1), LBv), UBv) : LBv;
            bx = fmaf(w, lx, bx);
            by = fmaf(w, ly, by);
            bz = fmaf(w, lz, bz);
        }
        out[po + 0] = bx + mx;
        out[po + 1] = by + my;
        out[po + 2] = bz + mz;
        out[dho + 0] = dx;
        out[dho + 1] = dy;
        out[dho + 2] = dz;
        out[dho + 3] = h / kk;
    }
}

extern "C" void kernel_launch(void* const* d_in, const int* in_sizes, int n_in,
                              void* d_out, int out_size, void* d_ws, size_t ws_size,
                              hipStream_t stream) {
    const float* verts  = (const float*)d_in[0];
    const float* smooth = (const float*)d_in[1];
    const float* dirs   = (const float*)d_in[2];
    float* out = (float*)d_out;

    // verts = NT*V*3, smooth = NT, dirs = D*3
    const int NT = in_sizes[1];
    const int D  = in_sizes[2] / 3;
    const int V  = in_sizes[0] / (3 * NT);
    const int SPLIT = (D + BLOCK - 1) / BLOCK;           // 1 dir per thread

    const size_t offDH  = (size_t)NT * D * 3;            // after points
    const size_t offMV  = offDH  + (size_t)NT * D * 4;   // after direction_h
    const size_t offDIR = offMV  + (size_t)NT * 3;       // after mean_v
    const size_t offLV  = offDIR + (size_t)D * 3;        // after directions
    const size_t offZ   = offLV  + (size_t)NT * V * 3;   // after local_vertices

    dim3 grid(NT * SPLIT);
    dim3 block(BLOCK);
    hipLaunchKernelGGL(mcnet_sreg, grid, block, 0, stream,
                       verts, smooth, dirs, out,
                       NT, V, D, SPLIT, offDH, offMV, offDIR, offLV, offZ);
}

// Round 2
// 87.954 us; speedup vs baseline: 1.0619x; 1.0619x over previous
//
#include <hip/hip_runtime.h>
#include <math.h>

#define BLOCK 256
#define DPB   64      // directions per block = one wave's lanes
#define NSUB  4       // vertex sub-chunks, one per wave
#define LBv 1e-20f
#define UBv 1e20f

// Raw HW transcendentals: v_log_f32 / v_exp_f32 (~1 ulp).
// Edge semantics used deliberately: log2(0) = -inf, exp2(-inf) = 0 (c1>0).
#if __has_builtin(__builtin_amdgcn_logf) && __has_builtin(__builtin_amdgcn_exp2f)
__device__ __forceinline__ float fast_log2(float x) { return __builtin_amdgcn_logf(x); }
__device__ __forceinline__ float fast_exp2(float x) { return __builtin_amdgcn_exp2f(x); }
#else
__device__ __forceinline__ float fast_log2(float x) { return log2f(x); }
__device__ __forceinline__ float fast_exp2(float x) { return exp2f(x); }
#endif

__global__ __launch_bounds__(BLOCK, 8) void mcnet_sreg(
    const float* __restrict__ verts,   // (NT, V, 3) f32
    const float* __restrict__ smooth,  // (NT,)      f32
    const float* __restrict__ dirs,    // (D, 3)     f32
    float* __restrict__ out,           // f32, chunks concatenated flat
    int NT, int V, int D, int SPLIT,
    size_t offDH, size_t offMV, size_t offDIR, size_t offLV, size_t offZ)
{
    __shared__ float red[12];                   // mean partials (4 waves x 3)
    __shared__ float acc[5][NSUB - 1][DPB];     // S,Wx,Wy,Wz,Ws partials

    const int tid  = threadIdx.x;
    const int lane = tid & 63;
    const int wid  = tid >> 6;
    const int tile = blockIdx.x / SPLIT;
    const int s    = blockIdx.x % SPLIT;

    const float* vp0 = verts + (size_t)tile * V * 3;

    // ---- mean: per-thread partial -> wave shfl_xor reduce -> 1 barrier ----
    float sx = 0.f, sy = 0.f, sz = 0.f;
    for (int v = tid; v < V; v += BLOCK) {
        sx += vp0[3 * v + 0]; sy += vp0[3 * v + 1]; sz += vp0[3 * v + 2];
    }
    #pragma unroll
    for (int off = 32; off > 0; off >>= 1) {
        sx += __shfl_xor(sx, off);
        sy += __shfl_xor(sy, off);
        sz += __shfl_xor(sz, off);
    }
    if (lane == 0) { red[wid * 3 + 0] = sx; red[wid * 3 + 1] = sy; red[wid * 3 + 2] = sz; }
    __syncthreads();
    const float inv = 1.0f / (float)V;
    const float mx = (red[0] + red[3] + red[6] + red[9])  * inv;
    const float my = (red[1] + red[4] + red[7] + red[10]) * inv;
    const float mz = (red[2] + red[5] + red[8] + red[11]) * inv;

    // ---- small outputs ----
    if (s == 0) {
        for (int v = tid; v < V; v += BLOCK) {
            size_t o = offLV + ((size_t)tile * V + v) * 3;
            out[o + 0] = vp0[3 * v + 0] - mx;
            out[o + 1] = vp0[3 * v + 1] - my;
            out[o + 2] = vp0[3 * v + 2] - mz;
        }
        if (tid == 0) {
            size_t mo = offMV + (size_t)tile * 3;
            out[mo + 0] = mx;
            out[mo + 1] = my;
            out[mo + 2] = mz;
        }
    }
    if (blockIdx.x == 0) {
        for (int i = tid; i < D * 3; i += BLOCK)
            out[offDIR + i] = dirs[i];
        if (tid < 2) out[offZ + tid] = 0.f;
    }

    // ---- 64 directions per block; each wave owns a V/4 vertex chunk ----
    const int d0     = s * DPB + lane;
    const bool active = (d0 < D);
    const int  d      = active ? d0 : (D - 1);

    const float dx = dirs[d * 3 + 0];
    const float dy = dirs[d * 3 + 1];
    const float dz = dirs[d * 3 + 2];
    const float pv = smooth[tile];
    const float c1 = pv - 1.f;
    const float Sthresh = (float)V * 1e-10f;

    // z = v.d - m.d : wave-uniform vertex reads (s_load), unnormalized sums,
    // mean-correct in the epilogue: sum w*lv = (sum w*v) - m*(sum w)
    const float nmd = -(mx * dx + my * dy + mz * dz);

    // force the chunk index into an SGPR so the vertex loads stay scalar
    const int sub  = __builtin_amdgcn_readfirstlane(wid);
    const int VC   = V >> 2;                       // verts per chunk
    const int vbeg = sub * VC;
    const int vend = (sub == NSUB - 1) ? V : vbeg + VC;

    float S = 0.f, Wx = 0.f, Wy = 0.f, Wz = 0.f, Ws = 0.f;

#define PROC1(vx, vy, vz) do {                                     \
        float z  = fmaf((vx), dx, fmaf((vy), dy, fmaf((vz), dz, nmd))); \
        float zc = fmaxf(z, 0.f);                                  \
        float l  = fast_log2(zc);          /* -inf at 0 */         \
        float w  = fast_exp2(c1 * l);      /* z^(p-1), 0 at z<=0 */\
        S  = fmaf(w, zc, S);                                       \
        Wx = fmaf(w, (vx), Wx);                                    \
        Wy = fmaf(w, (vy), Wy);                                    \
        Wz = fmaf(w, (vz), Wz);                                    \
        Ws += w;                                                   \
    } while (0)

    #pragma unroll 8
    for (int v = vbeg; v < vend; ++v)
        PROC1(vp0[3 * v + 0], vp0[3 * v + 1], vp0[3 * v + 2]);

    // ---- merge the 4 per-wave partials through LDS ----
    if (sub != 0) {
        acc[0][sub - 1][lane] = S;
        acc[1][sub - 1][lane] = Wx;
        acc[2][sub - 1][lane] = Wy;
        acc[3][sub - 1][lane] = Wz;
        acc[4][sub - 1][lane] = Ws;
    }
    __syncthreads();
    if (sub != 0) return;

    #pragma unroll
    for (int k = 0; k < NSUB - 1; ++k) {
        S  += acc[0][k][lane];
        Wx += acc[1][k][lane];
        Wy += acc[2][k][lane];
        Wz += acc[3][k][lane];
        Ws += acc[4][k][lane];
    }

    if (!active) return;

    size_t po  = ((size_t)tile * D + d) * 3;
    size_t dho = offDH + ((size_t)tile * D + d) * 4;

    if (S >= Sthresh) {
        // S >= V*1e-10 => zmax^p >= 1e-10: no k-rescale, exponents bounded,
        // LB floors negligible, UB clip unreachable.
        float h = fminf(fmaxf(fast_exp2(fast_log2(S) * (1.f / pv)), LBv), UBv);
        float scale = fast_exp2(-c1 * fast_log2(h));   // h^-(p-1)
        float ax = fmaf(-mx, Ws, Wx);                  // sum w*lv
        float ay = fmaf(-my, Ws, Wy);
        float az = fmaf(-mz, Ws, Wz);
        out[po + 0] = fmaf(ax, scale, mx);
        out[po + 1] = fmaf(ay, scale, my);
        out[po + 2] = fmaf(az, scale, mz);
        out[dho + 0] = dx;
        out[dho + 1] = dy;
        out[dho + 2] = dz;
        out[dho + 3] = h;                               // k == 1
    } else {
        // ---- literal reference semantics (cold; never taken for bench data) ----
        float zmax = 0.f;
        for (int v = 0; v < V; ++v) {
            float z = fmaf(vp0[3 * v] - mx, dx,
                      fmaf(vp0[3 * v + 1] - my, dy, (vp0[3 * v + 2] - mz) * dz));
            zmax = fmaxf(zmax, z);
        }
        float zm_log   = (zmax > 0.f) ? log10f(zmax) : -INFINITY;
        float exponent = zm_log * pv;
        float lk = (exponent < -20.f) ? (-20.f - exponent) / pv : 0.f;
        float kk = powf(10.f, fminf(fmaxf(ceilf(lk), 0.f), UBv));

        float sum = 0.f;
        for (int v = 0; v < V; ++v) {
            float z = fmaf(vp0[3 * v] - mx, dx,
                      fmaf(vp0[3 * v + 1] - my, dy, (vp0[3 * v + 2] - mz) * dz));
            float zms = fmaxf(z, 0.f) * kk;
            float w   = (zms > 0.f) ? fminf(fmaxf(powf(zms, pv), LBv), UBv) : 0.f;
            sum += w;
        }
        float h = fminf(fmaxf(powf(sum, 1.f / pv), LBv), UBv);

        float bx = 0.f, by = 0.f, bz = 0.f;
        for (int v = 0; v < V; ++v) {
            float lx = vp0[3 * v] - mx, ly = vp0[3 * v + 1] - my, lz = vp0[3 * v + 2] - mz;
            float z     = fmaf(lx, dx, fmaf(ly, dy, lz * dz));
            float zms   = fmaxf(z, 0.f) * kk;
            float ratio = zms / h;
            float w = (ratio > 0.f) ? fminf(fmaxf(powf(ratio, c1), LBv), UBv) : LBv;
            bx = fmaf(w, lx, bx);
            by = fmaf(w, ly, by);
            bz = fmaf(w, lz, bz);
        }
        out[po + 0] = bx + mx;
        out[po + 1] = by + my;
        out[po + 2] = bz + mz;
        out[dho + 0] = dx;
        out[dho + 1] = dy;
        out[dho + 2] = dz;
        out[dho + 3] = h / kk;
    }
}

extern "C" void kernel_launch(void* const* d_in, const int* in_sizes, int n_in,
                              void* d_out, int out_size, void* d_ws, size_t ws_size,
                              hipStream_t stream) {
    const float* verts  = (const float*)d_in[0];
    const float* smooth = (const float*)d_in[1];
    const float* dirs   = (const float*)d_in[2];
    float* out = (float*)d_out;

    // verts = NT*V*3, smooth = NT, dirs = D*3
    const int NT = in_sizes[1];
    const int D  = in_sizes[2] / 3;
    const int V  = in_sizes[0] / (3 * NT);
    const int SPLIT = (D + DPB - 1) / DPB;               // 64 dirs per block

    const size_t offDH  = (size_t)NT * D * 3;            // after points
    const size_t offMV  = offDH  + (size_t)NT * D * 4;   // after direction_h
    const size_t offDIR = offMV  + (size_t)NT * 3;       // after mean_v
    const size_t offLV  = offDIR + (size_t)D * 3;        // after directions
    const size_t offZ   = offLV  + (size_t)NT * V * 3;   // after local_vertices

    dim3 grid(NT * SPLIT);
    dim3 block(BLOCK);
    hipLaunchKernelGGL(mcnet_sreg, grid, block, 0, stream,
                       verts, smooth, dirs, out,
                       NT, V, D, SPLIT, offDH, offMV, offDIR, offLV, offZ);
}